// Round 1
// baseline (11.458 us; speedup 1.0000x reference)
//
#include <hip/hip_runtime.h>

// DirectionalConv2D: 5x5 wind-directional Gaussian blur, f32.
// B=4, H=W=512. out = clip(0.7 * (Σ w·patch)/(Σ w + 1e-8) + 0.3*fire, 0, 1)
// w_ij = exp(-((i-2)c + (j-2)s)^2 / (2*1.5^2)),  c = (u+1e-8)/r, s = v/r.
// Factorized: w_ij = A^{ai^2} * B^{aj^2} * g^{ai*aj} -> 3 exps/pixel.

constexpr int Wd = 512;
constexpr int Hd = 512;
constexpr float INV2SIG2 = 1.0f / 4.5f;   // 1/(2*sigma^2)
constexpr float BETA = 0.3f;

__global__ __launch_bounds__(256) void dirconv_kernel(
    const float* __restrict__ fire,
    const float* __restrict__ wu,
    const float* __restrict__ wv,
    float* __restrict__ out,
    int total)
{
    int t = blockIdx.x * 256 + threadIdx.x;
    int p = t << 2;                      // 4 consecutive x-pixels per thread
    if (p >= total) return;

    int rem = p & (Hd * Wd - 1);         // index within one image
    int y = rem >> 9;                    // /512
    int x = rem & (Wd - 1);              // multiple of 4
    const float* img = fire + (p - rem); // batch base

    float4 f4 = *reinterpret_cast<const float4*>(fire + p);
    float4 u4 = *reinterpret_cast<const float4*>(wu + p);
    float4 v4 = *reinterpret_cast<const float4*>(wv + p);

    float fa[4] = {f4.x, f4.y, f4.z, f4.w};
    float ua[4] = {u4.x, u4.y, u4.z, u4.w};
    float va[4] = {v4.x, v4.y, v4.z, v4.w};

    // Per-pixel weight factors (all unrolled -> registers)
    float A1[4], A4[4], B1[4], B4[4];
    float gp1[4], gp2[4], gp4[4], gm1[4], gm2[4], gm4[4];
    float S[4], Ws[4];

#pragma unroll
    for (int k = 0; k < 4; ++k) {
        float un = ua[k] + 1e-8f;
        float vv = va[k];
        float r2 = fmaf(un, un, vv * vv);
        r2 = (r2 < 1e-36f) ? 1e-36f : r2;
        float ir = __builtin_amdgcn_rsqf(r2);
        float c = un * ir;
        float s = vv * ir;
        float a1 = __expf(-INV2SIG2 * c * c);
        float b1 = __expf(-INV2SIG2 * s * s);
        float g  = __expf(-2.0f * INV2SIG2 * c * s);
        A1[k] = a1; { float a2 = a1 * a1; A4[k] = a2 * a2; }
        B1[k] = b1; { float b2 = b1 * b1; B4[k] = b2 * b2; }
        gp1[k] = g; gp2[k] = g * g; gp4[k] = gp2[k] * gp2[k];
        float gi = __builtin_amdgcn_rcpf(g);
        gm1[k] = gi; gm2[k] = gi * gi; gm4[k] = gm2[k] * gm2[k];
        S[k] = 0.0f;
        Ws[k] = 0.0f;
    }

#pragma unroll
    for (int di = 0; di < 5; ++di) {
        const int ai = di - 2;
        int row = y + ai;
        bool rv = ((unsigned)row < (unsigned)Hd);
        float4 Lv = make_float4(0.f, 0.f, 0.f, 0.f);
        float4 Mv = Lv;
        float4 Rv = Lv;
        if (rv) {
            const float* rp = img + row * Wd;
            Mv = *reinterpret_cast<const float4*>(rp + x);
            if (x >= 4)      Lv = *reinterpret_cast<const float4*>(rp + x - 4);
            if (x + 4 < Wd)  Rv = *reinterpret_cast<const float4*>(rp + x + 4);
        }
        // columns x-4 .. x+7; needed local indices 2..9
        float fv[12] = {Lv.x, Lv.y, Lv.z, Lv.w,
                        Mv.x, Mv.y, Mv.z, Mv.w,
                        Rv.x, Rv.y, Rv.z, Rv.w};
#pragma unroll
        for (int dj = 0; dj < 5; ++dj) {
            const int aj = dj - 2;
            const int prod = ai * aj;
#pragma unroll
            for (int k = 0; k < 4; ++k) {
                float wa = (ai == 0) ? 1.0f
                         : ((ai == 1 || ai == -1) ? A1[k] : A4[k]);
                float wb = (aj == 0) ? 1.0f
                         : ((aj == 1 || aj == -1) ? B1[k] : B4[k]);
                float w = wa * wb;
                if (prod == 1)       w *= gp1[k];
                else if (prod == -1) w *= gm1[k];
                else if (prod == 2)  w *= gp2[k];
                else if (prod == -2) w *= gm2[k];
                else if (prod == 4)  w *= gp4[k];
                else if (prod == -4) w *= gm4[k];
                Ws[k] += w;
                S[k] = fmaf(w, fv[k + dj + 2], S[k]);
            }
        }
    }

    float4 o;
#pragma unroll
    for (int k = 0; k < 4; ++k) {
        float inv = __builtin_amdgcn_rcpf(Ws[k] + 1e-8f);
        float sp = S[k] * inv;
        float r = fmaf(1.0f - BETA, sp, BETA * fa[k]);
        r = fminf(fmaxf(r, 0.0f), 1.0f);
        (&o.x)[k] = r;
    }
    *reinterpret_cast<float4*>(out + p) = o;
}

extern "C" void kernel_launch(void* const* d_in, const int* in_sizes, int n_in,
                              void* d_out, int out_size, void* d_ws, size_t ws_size,
                              hipStream_t stream) {
    const float* fire = (const float*)d_in[0];
    const float* wu   = (const float*)d_in[1];
    const float* wv   = (const float*)d_in[2];
    float* out        = (float*)d_out;
    int total = out_size;                     // B*H*W = 1048576
    int threads = (total + 3) / 4;
    int blocks = (threads + 255) / 256;
    dirconv_kernel<<<blocks, 256, 0, stream>>>(fire, wu, wv, out, total);
}